// Round 9
// baseline (118.801 us; speedup 1.0000x reference)
//
#include <hip/hip_runtime.h>
#include <hip/hip_bf16.h>
#include <cstdint>
#include <cstddef>

#define D_MODEL 1024
#define NHEADS  16
#define DEPTH   64
#define BATCH   2
#define SEQ     2048
#define M_TOT   (BATCH*SEQ)   // 4096
#define QK_SCALE 0.18033688011112042f   // 0.125 * log2(e): softmax done in exp2 domain

typedef __attribute__((ext_vector_type(8)))  __bf16 bf16x8;
typedef __attribute__((ext_vector_type(4)))  float  f32x4;
typedef __attribute__((ext_vector_type(16))) float  f32x16;

__device__ inline unsigned short f2bf(float f){
  unsigned u = __float_as_uint(f);
  u += 0x7FFFu + ((u>>16)&1u);
  return (unsigned short)(u>>16);
}
// pack two floats into u32 of 2x bf16 (RNE), single HW instr
__device__ inline unsigned cvtpk(float lo, float hi){
  unsigned r;
  asm("v_cvt_pk_bf16_f32 %0, %1, %2" : "=v"(r) : "v"(lo), "v"(hi));
  return r;
}
// 2^x via v_exp_f32 (no libm range fixup)
__device__ inline float fexp2(float x){
  float r;
  asm("v_exp_f32 %0, %1" : "=v"(r) : "v"(x));
  return r;
}
// swap bits 2 and 3 of an index (involution pi; used for V-s / O-d layouts)
__device__ inline int bswap23(int x){
  return (x & ~12) | ((x & 4) << 1) | ((x & 8) >> 1);
}

#define AS1(p) ((__attribute__((address_space(1))) void*)(p))
#define AS3(p) ((__attribute__((address_space(3))) void*)(p))

// ---------------- fp32 -> bf16, 3 tensors in one launch (z picks) ----------------
__global__ void cvt3(const float* __restrict__ q, const float* __restrict__ k,
                     const float* __restrict__ v,
                     unsigned short* oq, unsigned short* ok, unsigned short* ov, int n4){
  const float* in = blockIdx.z==0 ? q : blockIdx.z==1 ? k : v;
  unsigned short* out = blockIdx.z==0 ? oq : blockIdx.z==1 ? ok : ov;
  int i = blockIdx.x*blockDim.x + threadIdx.x;
  if (i >= n4) return;
  float4 val = ((const float4*)in)[i];
  ushort4 o;
  o.x = f2bf(val.x); o.y = f2bf(val.y); o.z = f2bf(val.z); o.w = f2bf(val.w);
  ((ushort4*)out)[i] = o;
}

// ---------------- W [K,N] fp32 -> Wt [N,K] bf16, 4 weights in one launch ----------
// z==3 (wo): K-index stored bit-2/3-swapped (pi) to match attn's O store order.
__global__ void tcvt4(const float* __restrict__ w0, const float* __restrict__ w1,
                      const float* __restrict__ w2, const float* __restrict__ w3,
                      unsigned short* o0, unsigned short* o1,
                      unsigned short* o2, unsigned short* o3){
  const float* W = blockIdx.z==0 ? w0 : blockIdx.z==1 ? w1 : blockIdx.z==2 ? w2 : w3;
  unsigned short* Wt = blockIdx.z==0 ? o0 : blockIdx.z==1 ? o1 : blockIdx.z==2 ? o2 : o3;
  const bool perm = (blockIdx.z == 3);
  __shared__ float t[32][33];
  int bx = blockIdx.x*32, by = blockIdx.y*32;
  for (int j = threadIdx.y; j < 32; j += 8)
    t[j][threadIdx.x] = W[(size_t)(by+j)*D_MODEL + bx + threadIdx.x];
  __syncthreads();
  for (int j = threadIdx.y; j < 32; j += 8){
    int col = by + threadIdx.x;            // k index
    if (perm) col = bswap23(col);
    Wt[(size_t)(bx+j)*D_MODEL + col] = f2bf(t[threadIdx.x][j]);
  }
}

// ---------------- projection GEMMs: 128x128 tile, BK=64, XOR-swizzled LDS ----------
#define BM 128
#define BN 128
#define BK 64
#define GK 1024

// LDS tile: [rows][128B] bf16, byte addr = row*128 + (col ^ ((row&7)<<4)).
// Staged via linear-dest global_load_lds with pre-swizzled global source
// (both-sides involution, m201 pattern). ROWS must be 64 or 128.
// Stage ROWS x 64 bf16 from P (row stride RSB bytes) at k-offset k0.
#define STAGE_TILE(lds, P, RSB, k0, ROWS) \
  _Pragma("unroll") \
  for (int i2=0; i2<(ROWS)/32; i2++){ \
    int x = i2*4096 + tid*16; \
    int row_ = x >> 7; \
    int cb_ = (x & 127) ^ ((row_&7)<<4); \
    __builtin_amdgcn_global_load_lds( \
      AS1((P) + (size_t)row_*(RSB) + (k0)*2 + cb_), \
      AS3((char*)(lds) + x), 16, 0, 0); \
  }

// fragment read: row, k-slice kk (0/1), lane-local
#define FRAG(lds, row_, kk) \
  (*(const bf16x8*)((const char*)(lds) + (row_)*128 + \
     (((kk)*64 + (lane>>4)*16) ^ (((row_)&7)<<4))))

// QKV projections fused into one launch: blockIdx.z = 0(Q) 1(K) 2(V)
__global__ __launch_bounds__(256) void gemm_qkv(
    const unsigned short* __restrict__ Xq, const unsigned short* __restrict__ Xk,
    const unsigned short* __restrict__ Xv,
    const unsigned short* __restrict__ Wq, const unsigned short* __restrict__ Wk,
    const unsigned short* __restrict__ Wv,
    const float* __restrict__ bq, const float* __restrict__ bk, const float* __restrict__ bv,
    unsigned short* Qh, unsigned short* Kh, unsigned short* Vth)
{
  __shared__ __align__(16) short As[BM*BK];   // 16 KB
  __shared__ __align__(16) short Bs[BN*BK];   // 16 KB
  const int z = blockIdx.z;
  const unsigned short* A  = z==0 ? Xq : z==1 ? Xk : Xv;
  const unsigned short* Bt = z==0 ? Wq : z==1 ? Wk : Wv;
  const float* bias        = z==0 ? bq : z==1 ? bk : bv;

  const int tid = threadIdx.x, lane = tid & 63, wave = tid >> 6;
  const int m0 = blockIdx.x*BM, n0 = blockIdx.y*BN;
  const int wm = wave >> 1, wn = wave & 1;

  f32x4 acc[4][4];
  #pragma unroll
  for (int i=0;i<4;i++)
    #pragma unroll
    for (int j=0;j<4;j++)
      acc[i][j] = (f32x4){0.f,0.f,0.f,0.f};

  const char* Abase = (const char*)A + (size_t)m0*GK*2;
  const char* Bbase = (const char*)Bt + (size_t)n0*GK*2;

  for (int k0 = 0; k0 < GK; k0 += BK){
    STAGE_TILE(As, Abase, GK*2, k0, BM)
    STAGE_TILE(Bs, Bbase, GK*2, k0, BN)
    __syncthreads();
    #pragma unroll
    for (int kk=0;kk<2;kk++){
      bf16x8 af[4], bfv[4];
      #pragma unroll
      for (int i=0;i<4;i++)
        af[i] = FRAG(As, wm*64 + i*16 + (lane&15), kk);
      #pragma unroll
      for (int j=0;j<4;j++)
        bfv[j] = FRAG(Bs, wn*64 + j*16 + (lane&15), kk);
      #pragma unroll
      for (int i=0;i<4;i++)
        #pragma unroll
        for (int j=0;j<4;j++)
          acc[i][j] = __builtin_amdgcn_mfma_f32_16x16x32_bf16(af[i], bfv[j], acc[i][j], 0,0,0);
    }
    __syncthreads();
  }

  #pragma unroll
  for (int i=0;i<4;i++)
    #pragma unroll
    for (int j=0;j<4;j++)
      #pragma unroll
      for (int r=0;r<4;r++){
        int gr = m0 + wm*64 + i*16 + (lane>>4)*4 + r;
        int gc = n0 + wn*64 + j*16 + (lane&15);
        float v = acc[i][j][r] + bias[gc];
        int b = gr>>11, s = gr&2047, h = gc>>6, d = gc&63;
        if (z == 0){
          v *= QK_SCALE;
          Qh[(((size_t)(b*NHEADS+h))*SEQ + s)*DEPTH + d] = f2bf(v);
        } else if (z == 1){
          Kh[(((size_t)(b*NHEADS+h))*SEQ + s)*DEPTH + d] = f2bf(v);
        } else {
          int sp = bswap23(s);
          Vth[(((size_t)(b*NHEADS+h))*DEPTH + d)*SEQ + sp] = f2bf(v);
        }
      }
}

// output projection: C fp32 [M,N] = A[M,K] @ Bt[N,K]^T + bias
// BM2=64 -> grid 512 = 2 blocks/CU; BK=64 swizzled like gemm_qkv.
#define BM2 64
__global__ __launch_bounds__(256) void gemm_out(
    const unsigned short* __restrict__ A,
    const unsigned short* __restrict__ Bt,
    const float* __restrict__ bias,
    float* __restrict__ Cout)
{
  __shared__ __align__(16) short As[BM2*BK];   // 8 KB
  __shared__ __align__(16) short Bs[BN*BK];    // 16 KB
  const int tid = threadIdx.x, lane = tid & 63, wave = tid >> 6;
  const int m0 = blockIdx.x*BM2, n0 = blockIdx.y*BN;
  const int wm = wave >> 1, wn = wave & 1;     // wave: 32 rows x 64 cols

  f32x4 acc[2][4];
  #pragma unroll
  for (int i=0;i<2;i++)
    #pragma unroll
    for (int j=0;j<4;j++)
      acc[i][j] = (f32x4){0.f,0.f,0.f,0.f};

  const char* Abase = (const char*)A + (size_t)m0*GK*2;
  const char* Bbase = (const char*)Bt + (size_t)n0*GK*2;

  for (int k0 = 0; k0 < GK; k0 += BK){
    STAGE_TILE(As, Abase, GK*2, k0, BM2)
    STAGE_TILE(Bs, Bbase, GK*2, k0, BN)
    __syncthreads();
    #pragma unroll
    for (int kk=0;kk<2;kk++){
      bf16x8 af[2], bfv[4];
      #pragma unroll
      for (int i=0;i<2;i++)
        af[i] = FRAG(As, wm*32 + i*16 + (lane&15), kk);
      #pragma unroll
      for (int j=0;j<4;j++)
        bfv[j] = FRAG(Bs, wn*64 + j*16 + (lane&15), kk);
      #pragma unroll
      for (int i=0;i<2;i++)
        #pragma unroll
        for (int j=0;j<4;j++)
          acc[i][j] = __builtin_amdgcn_mfma_f32_16x16x32_bf16(af[i], bfv[j], acc[i][j], 0,0,0);
    }
    __syncthreads();
  }

  #pragma unroll
  for (int i=0;i<2;i++)
    #pragma unroll
    for (int j=0;j<4;j++)
      #pragma unroll
      for (int r=0;r<4;r++){
        int gr = m0 + wm*32 + i*16 + (lane>>4)*4 + r;
        int gc = n0 + wn*64 + j*16 + (lane&15);
        Cout[(size_t)gr*D_MODEL + gc] = acc[i][j][r] + bias[gc];
      }
}

// ---------------- causal flash attention: concurrent complementary pair ----------
// Block: 512 threads = 8 waves. Waves 0-3 process q-tile jt=31-pj (long),
// waves 4-7 q-tile jt=pj (short); both share the same K/V staging (kv ranges
// nest). Within a tile: (qh=w&1, kh=(w>>1)&1) -> 32q x 32kv per round.
// Block duration = 32-pj rounds, grid (16, B*H) = 512 blocks = 2/CU ->
// ~16 resident waves/CU for most of the timeline. Fixed-max softmax:
// P = 2^(logit-16), -16 folded into MFMA C-init; kv-combine = plain add in
// LDS at the end. Qh,Kh: [BH][S][64]; Vt: [BH][64][S] pi on S;
// AO: [B][S][1024] pi on each head's d.
__global__ __launch_bounds__(512,4) void attn_fwd(
  const unsigned short* __restrict__ Qh,
  const unsigned short* __restrict__ Kh,
  const unsigned short* __restrict__ Vt,
  unsigned short* __restrict__ AO)
{
  __shared__ __align__(16) short Ks[2][4096];  // [kv][d] rows 128B, XOR-swizzled
  __shared__ __align__(16) short Vs[2][4096];  // [d][kv'] rows 128B, XOR-swizzled
  __shared__ float cbS[2][128];                // per-tile s partials

  const int tid = threadIdx.x, lane = tid & 63, w = tid >> 6;
  const int h = lane >> 5, ql = lane & 31;
  const int qh = w & 1, kh = (w >> 1) & 1, tl = w >> 2;  // tl: 0=long tile, 1=short
  const int pj = blockIdx.x, bh = blockIdx.y;
  const size_t hb = (size_t)bh * SEQ * DEPTH;
  const char* Kb = (const char*)(Kh + hb);
  const char* Vb = (const char*)(Vt + hb);
  const unsigned short* Qb = Qh + hb;
  const int bb = bh >> 4, hd = bh & 15;
  const int swz = (ql & 7) << 4;   // row&7 == ql&7 for all rows we read

  // stage K (waves 0-3) / V (waves 4-7): 2 x 1KB chunks per wave; LDS dest
  // linear, global source column pre-swizzled (involution byte ^ ((row&7)<<4)).
  auto STAGE = [&](int buf, int t){
    const int kv0 = t*64;
    #pragma unroll
    for (int i=0;i<2;i++){
      int c = (w&3)*2 + i;
      int x = c*1024 + lane*16;
      int row = x >> 7;
      int cb = (x & 127) ^ ((row&7)<<4);
      if (w < 4)
        __builtin_amdgcn_global_load_lds(
          AS1(Kb + (size_t)(kv0+row)*128 + cb),
          AS3((char*)&Ks[buf][0] + c*1024), 16, 0, 0);
      else
        __builtin_amdgcn_global_load_lds(
          AS1(Vb + ((size_t)row*SEQ + kv0)*2 + cb),
          AS3((char*)&Vs[buf][0] + c*1024), 16, 0, 0);
    }
  };

  const int jtw = tl ? pj : (31 - pj);     // this wave's q-tile
  const int Q0 = jtw*64 + qh*32;           // this wave's q base
  const int qmax = Q0 + 31;
  const int Tblock = 32 - pj;              // rounds (= long tile's need)

  // Q fragments: lane -> q = Q0+ql, d-slice 16c+8h..+7
  bf16x8 qreg[4];
  {
    const unsigned short* qp = Qb + (size_t)(Q0 + ql)*DEPTH + h*8;
    #pragma unroll
    for (int c=0;c<4;c++) qreg[c] = *(const bf16x8*)(qp + c*16);
  }

  f32x16 oacc[2];
  #pragma unroll
  for (int dh=0;dh<2;dh++)
    #pragma unroll
    for (int r=0;r<16;r++) oacc[dh][r] = 0.f;
  float s = 0.f;

  STAGE(0, 0);
  __syncthreads();
  int cur = 0;

  #pragma unroll 1
  for (int t = 0; t < Tblock; ++t){
    if (t+1 < Tblock) STAGE(cur^1, t+1);   // prefetch overlaps compute
    const int kvb = t*64 + kh*32;          // this wave's kv half-tile base

    if (kvb <= qmax){                      // else masked/out-of-range: skip
      // ---- S^T = K . Q^T : [32kv x 32q], C-init = -16 (softmax shift) ----
      f32x16 sa;
      #pragma unroll
      for (int r=0;r<16;r++) sa[r] = -16.0f;
      #pragma unroll
      for (int c=0;c<4;c++){
        bf16x8 kf = *(const bf16x8*)((const char*)&Ks[cur][0]
                      + (kh*32 + ql)*128 + ((32*c + 16*h) ^ swz));
        sa = __builtin_amdgcn_mfma_f32_32x32x16_bf16(kf, qreg[c], sa, 0,0,0);
      }

      // ---- causal mask (only when the half-tile straddles the diagonal) ----
      if (kvb + 31 > Q0){
        const int qg = Q0 + ql - kvb;      // kv pos > qg -> masked
        #pragma unroll
        for (int r=0;r<16;r++){
          int pos = (r&3) + 8*(r>>2) + 4*h;
          sa[r] = (pos > qg) ? -1e9f : sa[r];
        }
      }

      // ---- P = 2^sa; per-lane partial sum ----
      float s0=0.f, s1=0.f, s2=0.f, s3=0.f;
      #pragma unroll
      for (int r=0;r<16;r++){
        float p = fexp2(sa[r]);
        sa[r] = p;
        if ((r&3)==0) s0 += p; else if ((r&3)==1) s1 += p;
        else if ((r&3)==2) s2 += p; else s3 += p;
      }
      s += (s0+s1)+(s2+s3);

      // ---- pack P -> bf16 B-fragments, natural lane-local order ----
      bf16x8 pw[2];
      #pragma unroll
      for (int ks=0;ks<2;ks++){
        const int mm = 8*ks;
        union { unsigned u[4]; bf16x8 v; } pk;
        pk.u[0] = cvtpk(sa[mm+0], sa[mm+1]);
        pk.u[1] = cvtpk(sa[mm+2], sa[mm+3]);
        pk.u[2] = cvtpk(sa[mm+4], sa[mm+5]);
        pk.u[3] = cvtpk(sa[mm+6], sa[mm+7]);
        pw[ks] = pk.v;
      }

      // ---- O^T += V^T . P^T : [32d x 32q] x 2 d-halves ----
      #pragma unroll
      for (int ks=0;ks<2;ks++){
        #pragma unroll
        for (int dh=0;dh<2;dh++){
          bf16x8 vf = *(const bf16x8*)((const char*)&Vs[cur][0]
                        + (dh*32 + ql)*128 + ((kh*64 + ks*32 + 16*h) ^ swz));
          oacc[dh] = __builtin_amdgcn_mfma_f32_32x32x16_bf16(vf, pw[ks], oacc[dh], 0,0,0);
        }
      }
    }

    __syncthreads();
    cur ^= 1;
  }

  // ---- kv-split combine per tile: kh=1 publish (O,s); kh=0 merge + store ----
  // tile 0 (long) reuses Ks region (16KB), tile 1 (short) reuses Vs region.
  float* cbO  = (tl == 0) ? (float*)&Ks[0][0] : (float*)&Vs[0][0];
  float* cbSp = &cbS[tl][0];
  if (kh == 1){
    #pragma unroll
    for (int dh=0;dh<2;dh++)
      #pragma unroll
      for (int r=0;r<16;r++)
        cbO[(dh*16+r)*128 + qh*64 + lane] = oacc[dh][r];
    cbSp[qh*64 + lane] = s;
  }
  __syncthreads();
  if (kh == 0){
    #pragma unroll
    for (int dh=0;dh<2;dh++)
      #pragma unroll
      for (int r=0;r<16;r++)
        oacc[dh][r] += cbO[(dh*16+r)*128 + qh*64 + lane];
    s += cbSp[qh*64 + lane];
    float st = s + __shfl_xor(s, 32, 64);
    float inv = 1.0f / st;
    #pragma unroll
    for (int dh=0;dh<2;dh++)
      #pragma unroll
      for (int r=0;r<16;r++) oacc[dh][r] *= inv;

    unsigned short* orow = AO + ((size_t)bb*SEQ + (Q0 + ql))*D_MODEL + hd*DEPTH;
    #pragma unroll
    for (int dh=0;dh<2;dh++)
      #pragma unroll
      for (int g=0; g<2; g++){
        uint4 st4;
        st4.x = cvtpk(oacc[dh][8*g+0], oacc[dh][8*g+1]);
        st4.y = cvtpk(oacc[dh][8*g+2], oacc[dh][8*g+3]);
        st4.z = cvtpk(oacc[dh][8*g+4], oacc[dh][8*g+5]);
        st4.w = cvtpk(oacc[dh][8*g+6], oacc[dh][8*g+7]);
        *(uint4*)(orow + dh*32 + g*16 + h*8) = st4;
      }
  }
}

// ---------------- launcher ----------------
extern "C" void kernel_launch(void* const* d_in, const int* in_sizes, int n_in,
                              void* d_out, int out_size, void* d_ws, size_t ws_size,
                              hipStream_t stream) {
  const float* query  = (const float*)d_in[0];
  const float* key_in = (const float*)d_in[1];
  const float* value  = (const float*)d_in[2];
  // d_in[3] = mask (unused; causal handled analytically)
  const float* wq = (const float*)d_in[4];
  const float* bq = (const float*)d_in[5];
  const float* wk = (const float*)d_in[6];
  const float* bk = (const float*)d_in[7];
  const float* wv = (const float*)d_in[8];
  const float* bv = (const float*)d_in[9];
  const float* wo = (const float*)d_in[10];
  const float* bo = (const float*)d_in[11];

  char* ws = (char*)d_ws;
  const size_t MB = 1u<<20;
  unsigned short* Xq  = (unsigned short*)(ws + 0*MB);
  unsigned short* Xk  = (unsigned short*)(ws + 8*MB);
  unsigned short* Xv  = (unsigned short*)(ws + 16*MB);
  unsigned short* Wtq = (unsigned short*)(ws + 24*MB);
  unsigned short* Wtk = (unsigned short*)(ws + 26*MB);
  unsigned short* Wtv = (unsigned short*)(ws + 28*MB);
  unsigned short* Wto = (unsigned short*)(ws + 30*MB);  // pi-permuted K dim
  unsigned short* Qh  = (unsigned short*)(ws + 32*MB);  // [B,H,S,D] (pre-scaled)
  unsigned short* Kh  = (unsigned short*)(ws + 40*MB);  // [B,H,S,D]
  unsigned short* Vth = (unsigned short*)(ws + 48*MB);  // [B,H,D,S] pi on S
  unsigned short* AO  = (unsigned short*)(ws + 56*MB);  // [B,S,1024] pi on d per head

  const int n4 = (M_TOT*D_MODEL)/4;
  cvt3<<<dim3(n4/256,1,3), 256, 0, stream>>>(query, key_in, value, Xq, Xk, Xv, n4);
  tcvt4<<<dim3(32,32,4), dim3(32,8), 0, stream>>>(wq, wk, wv, wo, Wtq, Wtk, Wtv, Wto);

  gemm_qkv<<<dim3(M_TOT/BM, D_MODEL/BN, 3), 256, 0, stream>>>(
      Xq, Xk, Xv, Wtq, Wtk, Wtv, bq, bk, bv, Qh, Kh, Vth);

  attn_fwd<<<dim3(16, BATCH*NHEADS), 512, 0, stream>>>(Qh, Kh, Vth, AO);

  gemm_out<<<dim3(M_TOT/BM2, D_MODEL/BN), 256, 0, stream>>>(AO, Wto, bo, (float*)d_out);
}

// Round 10
// 105.617 us; speedup vs baseline: 1.1248x; 1.1248x over previous
//
#include <hip/hip_runtime.h>
#include <hip/hip_bf16.h>
#include <cstdint>
#include <cstddef>

#define D_MODEL 1024
#define NHEADS  16
#define DEPTH   64
#define BATCH   2
#define SEQ     2048
#define M_TOT   (BATCH*SEQ)   // 4096
#define QK_SCALE 0.18033688011112042f   // 0.125 * log2(e): softmax done in exp2 domain

typedef __attribute__((ext_vector_type(8)))  __bf16 bf16x8;
typedef __attribute__((ext_vector_type(4)))  float  f32x4;
typedef __attribute__((ext_vector_type(16))) float  f32x16;

__device__ inline unsigned short f2bf(float f){
  unsigned u = __float_as_uint(f);
  u += 0x7FFFu + ((u>>16)&1u);
  return (unsigned short)(u>>16);
}
// pack two floats into u32 of 2x bf16 (RNE), single HW instr
__device__ inline unsigned cvtpk(float lo, float hi){
  unsigned r;
  asm("v_cvt_pk_bf16_f32 %0, %1, %2" : "=v"(r) : "v"(lo), "v"(hi));
  return r;
}
// 2^x via v_exp_f32 (no libm range fixup)
__device__ inline float fexp2(float x){
  float r;
  asm("v_exp_f32 %0, %1" : "=v"(r) : "v"(x));
  return r;
}
// swap bits 2 and 3 of an index (involution pi; used for V-s / O-d layouts)
__device__ inline int bswap23(int x){
  return (x & ~12) | ((x & 4) << 1) | ((x & 8) >> 1);
}

#define AS1(p) ((__attribute__((address_space(1))) void*)(p))
#define AS3(p) ((__attribute__((address_space(3))) void*)(p))

// ---------------- W [K,N] fp32 -> Wt [N,K] bf16, 4 weights in one launch ----------
// z==3 (wo): K-index stored bit-2/3-swapped (pi) to match attn's O store order.
__global__ void tcvt4(const float* __restrict__ w0, const float* __restrict__ w1,
                      const float* __restrict__ w2, const float* __restrict__ w3,
                      unsigned short* o0, unsigned short* o1,
                      unsigned short* o2, unsigned short* o3){
  const float* W = blockIdx.z==0 ? w0 : blockIdx.z==1 ? w1 : blockIdx.z==2 ? w2 : w3;
  unsigned short* Wt = blockIdx.z==0 ? o0 : blockIdx.z==1 ? o1 : blockIdx.z==2 ? o2 : o3;
  const bool perm = (blockIdx.z == 3);
  __shared__ float t[32][33];
  int bx = blockIdx.x*32, by = blockIdx.y*32;
  for (int j = threadIdx.y; j < 32; j += 8)
    t[j][threadIdx.x] = W[(size_t)(by+j)*D_MODEL + bx + threadIdx.x];
  __syncthreads();
  for (int j = threadIdx.y; j < 32; j += 8){
    int col = by + threadIdx.x;            // k index
    if (perm) col = bswap23(col);
    Wt[(size_t)(bx+j)*D_MODEL + col] = f2bf(t[threadIdx.x][j]);
  }
}

// ---------------- projection GEMMs: 128x128 tile, BK=32 (R8 m97 structure) ----------
#define BM 128
#define BN 128
#define BK 32
#define GK 1024

// QKV projections fused into one launch: blockIdx.z = 0(Q) 1(K) 2(V).
// A operand read DIRECTLY from fp32 inputs: reg-staged (float4 x4 ->
// v_cvt_pk_bf16_f32 -> ds_write_b128); prefetch of step k+1 issued AFTER the
// post-stage barrier so the barrier never drains it (cvt's implicit vmcnt
// wait sits after a full MFMA phase). B staged via global_load_lds (bf16 Wt).
__global__ __launch_bounds__(256,2) void gemm_qkv(
    const float* __restrict__ Xfq, const float* __restrict__ Xfk,
    const float* __restrict__ Xfv,
    const unsigned short* __restrict__ Wq, const unsigned short* __restrict__ Wk,
    const unsigned short* __restrict__ Wv,
    const float* __restrict__ bq, const float* __restrict__ bk, const float* __restrict__ bv,
    unsigned short* Qh, unsigned short* Kh, unsigned short* Vth)
{
  __shared__ __align__(16) short As[BM*BK];   // 8 KB, rows of 64 B
  __shared__ __align__(16) short Bs[BN*BK];   // 8 KB
  const int z = blockIdx.z;
  const float* Af          = z==0 ? Xfq : z==1 ? Xfk : Xfv;
  const unsigned short* Bt = z==0 ? Wq  : z==1 ? Wk  : Wv;
  const float* bias        = z==0 ? bq  : z==1 ? bk  : bv;

  const int tid = threadIdx.x, lane = tid & 63, wave = tid >> 6;
  const int m0 = blockIdx.x*BM, n0 = blockIdx.y*BN;
  const int wm = wave >> 1, wn = wave & 1;

  f32x4 acc[4][4];
  #pragma unroll
  for (int i=0;i<4;i++)
    #pragma unroll
    for (int j=0;j<4;j++)
      acc[i][j] = (f32x4){0.f,0.f,0.f,0.f};

  const char* Afb   = (const char*)Af + (size_t)m0*GK*4;   // fp32 A panel
  const char* Bbase = (const char*)Bt + (size_t)n0*GK*2;
  const int arow = tid >> 2;          // row within 64-row chunk
  const int acb  = (tid & 3) * 32;    // fp32 byte col (32B = 8 floats)

  float4 alo[2], ahi[2];
  auto LOADA = [&](int k0){
    #pragma unroll
    for (int c=0;c<2;c++){
      const char* p = Afb + (size_t)(c*64 + arow)*(GK*4) + k0*4 + acb;
      alo[c] = *(const float4*)p;
      ahi[c] = *(const float4*)(p + 16);
    }
  };

  LOADA(0);
  for (int k0 = 0; k0 < GK; k0 += BK){
    // convert this step's A to bf16 (vmcnt wait lands here, after prior MFMA phase)
    uint4 pk[2];
    #pragma unroll
    for (int c=0;c<2;c++){
      pk[c].x = cvtpk(alo[c].x, alo[c].y);
      pk[c].y = cvtpk(alo[c].z, alo[c].w);
      pk[c].z = cvtpk(ahi[c].x, ahi[c].y);
      pk[c].w = cvtpk(ahi[c].z, ahi[c].w);
    }
    __syncthreads();                       // previous step's ds_reads complete
    #pragma unroll
    for (int c=0;c<2;c++)
      *(uint4*)((char*)As + c*4096 + tid*16) = pk[c];
    #pragma unroll
    for (int c=0;c<2;c++)
      __builtin_amdgcn_global_load_lds(
        AS1(Bbase + (size_t)(c*64 + arow)*(GK*2) + k0*2 + (tid&3)*16),
        AS3((char*)Bs + c*4096 + tid*16), 16, 0, 0);
    __syncthreads();                       // ds_write lgkm + B vmcnt (L2-hot)
    if (k0 + BK < GK) LOADA(k0 + BK);      // prefetch: hidden under MFMA phase

    bf16x8 af[4], bfv[4];
    #pragma unroll
    for (int i=0;i<4;i++)
      af[i] = *(const bf16x8*)((const char*)As + (wm*64 + i*16 + (lane&15))*64 + (lane>>4)*16);
    #pragma unroll
    for (int j=0;j<4;j++)
      bfv[j] = *(const bf16x8*)((const char*)Bs + (wn*64 + j*16 + (lane&15))*64 + (lane>>4)*16);
    #pragma unroll
    for (int i=0;i<4;i++)
      #pragma unroll
      for (int j=0;j<4;j++)
        acc[i][j] = __builtin_amdgcn_mfma_f32_16x16x32_bf16(af[i], bfv[j], acc[i][j], 0,0,0);
  }

  #pragma unroll
  for (int i=0;i<4;i++)
    #pragma unroll
    for (int j=0;j<4;j++)
      #pragma unroll
      for (int r=0;r<4;r++){
        int gr = m0 + wm*64 + i*16 + (lane>>4)*4 + r;
        int gc = n0 + wn*64 + j*16 + (lane&15);
        float v = acc[i][j][r] + bias[gc];
        int b = gr>>11, s = gr&2047, h = gc>>6, d = gc&63;
        if (z == 0){
          v *= QK_SCALE;
          Qh[(((size_t)(b*NHEADS+h))*SEQ + s)*DEPTH + d] = f2bf(v);
        } else if (z == 1){
          Kh[(((size_t)(b*NHEADS+h))*SEQ + s)*DEPTH + d] = f2bf(v);
        } else {
          int sp = bswap23(s);
          Vth[(((size_t)(b*NHEADS+h))*DEPTH + d)*SEQ + sp] = f2bf(v);
        }
      }
}

// output projection: C fp32 [M,N] = A[M,K] @ Bt[N,K]^T + bias  (exact R8 version)
// BM2=64 -> grid 512 = 2 blocks/CU.
#define BM2 64
__global__ __launch_bounds__(256,2) void gemm_out(
    const unsigned short* __restrict__ A,
    const unsigned short* __restrict__ Bt,
    const float* __restrict__ bias,
    float* __restrict__ Cout)
{
  __shared__ __align__(16) short As[BM2*BK];   // 4 KB
  __shared__ __align__(16) short Bs[BN*BK];    // 8 KB
  const int tid = threadIdx.x, lane = tid & 63, wave = tid >> 6;
  const int m0 = blockIdx.x*BM2, n0 = blockIdx.y*BN;
  const int wm = wave >> 1, wn = wave & 1;     // wave: 32 rows x 64 cols

  f32x4 acc[2][4];
  #pragma unroll
  for (int i=0;i<2;i++)
    #pragma unroll
    for (int j=0;j<4;j++)
      acc[i][j] = (f32x4){0.f,0.f,0.f,0.f};

  const char* Abase = (const char*)A + (size_t)m0*GK*2;
  const char* Bbase = (const char*)Bt + (size_t)n0*GK*2;

  for (int k0 = 0; k0 < GK; k0 += BK){
    __builtin_amdgcn_global_load_lds(
      AS1(Abase + (size_t)(tid>>2)*(GK*2) + k0*2 + (tid&3)*16),
      AS3((char*)As + tid*16), 16, 0, 0);
    #pragma unroll
    for (int c=0;c<2;c++)
      __builtin_amdgcn_global_load_lds(
        AS1(Bbase + (size_t)(c*64 + (tid>>2))*(GK*2) + k0*2 + (tid&3)*16),
        AS3((char*)Bs + c*4096 + tid*16), 16, 0, 0);
    __syncthreads();
    bf16x8 af[2], bfv[4];
    #pragma unroll
    for (int i=0;i<2;i++)
      af[i] = *(const bf16x8*)((const char*)As + (wm*32 + i*16 + (lane&15))*64 + (lane>>4)*16);
    #pragma unroll
    for (int j=0;j<4;j++)
      bfv[j] = *(const bf16x8*)((const char*)Bs + (wn*64 + j*16 + (lane&15))*64 + (lane>>4)*16);
    #pragma unroll
    for (int i=0;i<2;i++)
      #pragma unroll
      for (int j=0;j<4;j++)
        acc[i][j] = __builtin_amdgcn_mfma_f32_16x16x32_bf16(af[i], bfv[j], acc[i][j], 0,0,0);
    __syncthreads();
  }

  #pragma unroll
  for (int i=0;i<2;i++)
    #pragma unroll
    for (int j=0;j<4;j++)
      #pragma unroll
      for (int r=0;r<4;r++){
        int gr = m0 + wm*32 + i*16 + (lane>>4)*4 + r;
        int gc = n0 + wn*64 + j*16 + (lane&15);
        Cout[(size_t)gr*D_MODEL + gc] = acc[i][j][r] + bias[gc];
      }
}

// ---------------- causal flash attention: concurrent complementary pair ----------
// (unchanged from R8) Block: 512 threads = 8 waves. Waves 0-3 process q-tile
// jt=31-pj (long), waves 4-7 q-tile jt=pj (short); shared K/V staging.
// (qh=w&1, kh=(w>>1)&1) -> 32q x 32kv per round. Fixed-max softmax:
// P = 2^(logit-16), -16 folded into MFMA C-init; kv-combine = plain add.
__global__ __launch_bounds__(512,4) void attn_fwd(
  const unsigned short* __restrict__ Qh,
  const unsigned short* __restrict__ Kh,
  const unsigned short* __restrict__ Vt,
  unsigned short* __restrict__ AO)
{
  __shared__ __align__(16) short Ks[2][4096];  // [kv][d] rows 128B, XOR-swizzled
  __shared__ __align__(16) short Vs[2][4096];  // [d][kv'] rows 128B, XOR-swizzled
  __shared__ float cbS[2][128];                // per-tile s partials

  const int tid = threadIdx.x, lane = tid & 63, w = tid >> 6;
  const int h = lane >> 5, ql = lane & 31;
  const int qh = w & 1, kh = (w >> 1) & 1, tl = w >> 2;  // tl: 0=long tile, 1=short
  const int pj = blockIdx.x, bh = blockIdx.y;
  const size_t hb = (size_t)bh * SEQ * DEPTH;
  const char* Kb = (const char*)(Kh + hb);
  const char* Vb = (const char*)(Vt + hb);
  const unsigned short* Qb = Qh + hb;
  const int bb = bh >> 4, hd = bh & 15;
  const int swz = (ql & 7) << 4;   // row&7 == ql&7 for all rows we read

  auto STAGE = [&](int buf, int t){
    const int kv0 = t*64;
    #pragma unroll
    for (int i=0;i<2;i++){
      int c = (w&3)*2 + i;
      int x = c*1024 + lane*16;
      int row = x >> 7;
      int cb = (x & 127) ^ ((row&7)<<4);
      if (w < 4)
        __builtin_amdgcn_global_load_lds(
          AS1(Kb + (size_t)(kv0+row)*128 + cb),
          AS3((char*)&Ks[buf][0] + c*1024), 16, 0, 0);
      else
        __builtin_amdgcn_global_load_lds(
          AS1(Vb + ((size_t)row*SEQ + kv0)*2 + cb),
          AS3((char*)&Vs[buf][0] + c*1024), 16, 0, 0);
    }
  };

  const int jtw = tl ? pj : (31 - pj);     // this wave's q-tile
  const int Q0 = jtw*64 + qh*32;           // this wave's q base
  const int qmax = Q0 + 31;
  const int Tblock = 32 - pj;              // rounds (= long tile's need)

  bf16x8 qreg[4];
  {
    const unsigned short* qp = Qb + (size_t)(Q0 + ql)*DEPTH + h*8;
    #pragma unroll
    for (int c=0;c<4;c++) qreg[c] = *(const bf16x8*)(qp + c*16);
  }

  f32x16 oacc[2];
  #pragma unroll
  for (int dh=0;dh<2;dh++)
    #pragma unroll
    for (int r=0;r<16;r++) oacc[dh][r] = 0.f;
  float s = 0.f;

  STAGE(0, 0);
  __syncthreads();
  int cur = 0;

  #pragma unroll 1
  for (int t = 0; t < Tblock; ++t){
    if (t+1 < Tblock) STAGE(cur^1, t+1);   // prefetch overlaps compute
    const int kvb = t*64 + kh*32;          // this wave's kv half-tile base

    if (kvb <= qmax){                      // else masked/out-of-range: skip
      f32x16 sa;
      #pragma unroll
      for (int r=0;r<16;r++) sa[r] = -16.0f;
      #pragma unroll
      for (int c=0;c<4;c++){
        bf16x8 kf = *(const bf16x8*)((const char*)&Ks[cur][0]
                      + (kh*32 + ql)*128 + ((32*c + 16*h) ^ swz));
        sa = __builtin_amdgcn_mfma_f32_32x32x16_bf16(kf, qreg[c], sa, 0,0,0);
      }

      if (kvb + 31 > Q0){
        const int qg = Q0 + ql - kvb;      // kv pos > qg -> masked
        #pragma unroll
        for (int r=0;r<16;r++){
          int pos = (r&3) + 8*(r>>2) + 4*h;
          sa[r] = (pos > qg) ? -1e9f : sa[r];
        }
      }

      float s0=0.f, s1=0.f, s2=0.f, s3=0.f;
      #pragma unroll
      for (int r=0;r<16;r++){
        float p = fexp2(sa[r]);
        sa[r] = p;
        if ((r&3)==0) s0 += p; else if ((r&3)==1) s1 += p;
        else if ((r&3)==2) s2 += p; else s3 += p;
      }
      s += (s0+s1)+(s2+s3);

      bf16x8 pw[2];
      #pragma unroll
      for (int ks=0;ks<2;ks++){
        const int mm = 8*ks;
        union { unsigned u[4]; bf16x8 v; } pk;
        pk.u[0] = cvtpk(sa[mm+0], sa[mm+1]);
        pk.u[1] = cvtpk(sa[mm+2], sa[mm+3]);
        pk.u[2] = cvtpk(sa[mm+4], sa[mm+5]);
        pk.u[3] = cvtpk(sa[mm+6], sa[mm+7]);
        pw[ks] = pk.v;
      }

      #pragma unroll
      for (int ks=0;ks<2;ks++){
        #pragma unroll
        for (int dh=0;dh<2;dh++){
          bf16x8 vf = *(const bf16x8*)((const char*)&Vs[cur][0]
                        + (dh*32 + ql)*128 + ((kh*64 + ks*32 + 16*h) ^ swz));
          oacc[dh] = __builtin_amdgcn_mfma_f32_32x32x16_bf16(vf, pw[ks], oacc[dh], 0,0,0);
        }
      }
    }

    __syncthreads();
    cur ^= 1;
  }

  float* cbO  = (tl == 0) ? (float*)&Ks[0][0] : (float*)&Vs[0][0];
  float* cbSp = &cbS[tl][0];
  if (kh == 1){
    #pragma unroll
    for (int dh=0;dh<2;dh++)
      #pragma unroll
      for (int r=0;r<16;r++)
        cbO[(dh*16+r)*128 + qh*64 + lane] = oacc[dh][r];
    cbSp[qh*64 + lane] = s;
  }
  __syncthreads();
  if (kh == 0){
    #pragma unroll
    for (int dh=0;dh<2;dh++)
      #pragma unroll
      for (int r=0;r<16;r++)
        oacc[dh][r] += cbO[(dh*16+r)*128 + qh*64 + lane];
    s += cbSp[qh*64 + lane];
    float st = s + __shfl_xor(s, 32, 64);
    float inv = 1.0f / st;
    #pragma unroll
    for (int dh=0;dh<2;dh++)
      #pragma unroll
      for (int r=0;r<16;r++) oacc[dh][r] *= inv;

    unsigned short* orow = AO + ((size_t)bb*SEQ + (Q0 + ql))*D_MODEL + hd*DEPTH;
    #pragma unroll
    for (int dh=0;dh<2;dh++)
      #pragma unroll
      for (int g=0; g<2; g++){
        uint4 st4;
        st4.x = cvtpk(oacc[dh][8*g+0], oacc[dh][8*g+1]);
        st4.y = cvtpk(oacc[dh][8*g+2], oacc[dh][8*g+3]);
        st4.z = cvtpk(oacc[dh][8*g+4], oacc[dh][8*g+5]);
        st4.w = cvtpk(oacc[dh][8*g+6], oacc[dh][8*g+7]);
        *(uint4*)(orow + dh*32 + g*16 + h*8) = st4;
      }
  }
}

// ---------------- launcher ----------------
extern "C" void kernel_launch(void* const* d_in, const int* in_sizes, int n_in,
                              void* d_out, int out_size, void* d_ws, size_t ws_size,
                              hipStream_t stream) {
  const float* query  = (const float*)d_in[0];
  const float* key_in = (const float*)d_in[1];
  const float* value  = (const float*)d_in[2];
  // d_in[3] = mask (unused; causal handled analytically)
  const float* wq = (const float*)d_in[4];
  const float* bq = (const float*)d_in[5];
  const float* wk = (const float*)d_in[6];
  const float* bk = (const float*)d_in[7];
  const float* wv = (const float*)d_in[8];
  const float* bv = (const float*)d_in[9];
  const float* wo = (const float*)d_in[10];
  const float* bo = (const float*)d_in[11];

  char* ws = (char*)d_ws;
  const size_t MB = 1u<<20;
  unsigned short* Wtq = (unsigned short*)(ws + 24*MB);
  unsigned short* Wtk = (unsigned short*)(ws + 26*MB);
  unsigned short* Wtv = (unsigned short*)(ws + 28*MB);
  unsigned short* Wto = (unsigned short*)(ws + 30*MB);  // pi-permuted K dim
  unsigned short* Qh  = (unsigned short*)(ws + 32*MB);  // [B,H,S,D] (pre-scaled)
  unsigned short* Kh  = (unsigned short*)(ws + 40*MB);  // [B,H,S,D]
  unsigned short* Vth = (unsigned short*)(ws + 48*MB);  // [B,H,D,S] pi on S
  unsigned short* AO  = (unsigned short*)(ws + 56*MB);  // [B,S,1024] pi on d per head

  tcvt4<<<dim3(32,32,4), dim3(32,8), 0, stream>>>(wq, wk, wv, wo, Wtq, Wtk, Wtv, Wto);

  gemm_qkv<<<dim3(M_TOT/BM, D_MODEL/BN, 3), 256, 0, stream>>>(
      query, key_in, value, Wtq, Wtk, Wtv, bq, bk, bv, Qh, Kh, Vth);

  attn_fwd<<<dim3(16, BATCH*NHEADS), 512, 0, stream>>>(Qh, Kh, Vth, AO);

  gemm_out<<<dim3(M_TOT/BM2, D_MODEL/BN), 256, 0, stream>>>(AO, Wto, bo, (float*)d_out);
}